// Round 4
// baseline (972.139 us; speedup 1.0000x reference)
//
#include <hip/hip_runtime.h>
#include <hip/hip_bf16.h>

#define F 128
#define SLABS 8
#define SF 16   // feats per slab

static __device__ __forceinline__ unsigned short f2bf(float f) {
    unsigned int u = __float_as_uint(f);
    unsigned int r = (u + 0x7fffu + ((u >> 16) & 1u)) >> 16;   // RTN-even
    return (unsigned short)r;
}

#define BF2X(p) __uint_as_float((p) << 16)
#define BF2Y(p) __uint_as_float((p) & 0xffff0000u)

// ---------------- CSR build ----------------

__global__ void count_edges_k(const int* __restrict__ col, int* __restrict__ cnt, int E) {
    int e0 = (blockIdx.x * 256 + threadIdx.x) * 4;
    if (e0 + 4 <= E) {
        int4 c = *(const int4*)&col[e0];
        atomicAdd(&cnt[c.x], 1);
        atomicAdd(&cnt[c.y], 1);
        atomicAdd(&cnt[c.z], 1);
        atomicAdd(&cnt[c.w], 1);
    } else {
        for (int e = e0; e < E; e++) atomicAdd(&cnt[col[e]], 1);
    }
}

__global__ void scan1_k(const int* __restrict__ cnt, int* __restrict__ offs,
                        float* __restrict__ dinv, int* __restrict__ bsum, int n) {
    __shared__ int s[1024];
    int tid = threadIdx.x;
    int i = blockIdx.x * 1024 + tid;
    int v = (i < n) ? cnt[i] : 0;
    s[tid] = v;
    __syncthreads();
    for (int off = 1; off < 1024; off <<= 1) {
        int t = (tid >= off) ? s[tid - off] : 0;
        __syncthreads();
        s[tid] += t;
        __syncthreads();
    }
    if (i < n) {
        offs[i] = s[tid] - v;
        dinv[i] = rsqrtf((float)(v + 1));
    }
    if (tid == 1023) bsum[blockIdx.x] = s[1023];
}

__global__ void scan2_k(int* bsum, int nb) {
    __shared__ int s[128];
    int tid = threadIdx.x;
    int v = (tid < nb) ? bsum[tid] : 0;
    s[tid] = v;
    __syncthreads();
    for (int off = 1; off < 128; off <<= 1) {
        int t = (tid >= off) ? s[tid - off] : 0;
        __syncthreads();
        s[tid] += t;
        __syncthreads();
    }
    if (tid < nb) bsum[tid] = s[tid] - v;
}

__global__ void scan3_k(int* __restrict__ offs, int* __restrict__ cursor,
                        const int* __restrict__ bsum, int n, int E) {
    int i = blockIdx.x * 1024 + threadIdx.x;
    if (i < n) {
        int o = offs[i] + bsum[blockIdx.x];
        offs[i] = o;
        cursor[i] = o;
    }
    if (i == n) offs[n] = E;
}

__global__ void fill_k(const int* __restrict__ row, const int* __restrict__ col,
                       int* __restrict__ cursor, int* __restrict__ src, int E) {
    int e = blockIdx.x * 256 + threadIdx.x;
    if (e < E) {
        int v = col[e];
        int pos = atomicAdd(&cursor[v], 1);
        src[pos] = row[e];
    }
}

// ---------------- GEMM: Yslab[p][r][16] = bf16( dinv[r] * (X[r,:] @ W) ) ----------------
// BF16IN=0: X is f32 row-major [n][128]. BF16IN=1: X is bf16 slab-major [8][n][16].

template <int BF16IN>
__global__ __launch_bounds__(256) void gemm_scale_k(const void* __restrict__ Xin,
                                                    const float* __restrict__ W,
                                                    const float* __restrict__ dinv,
                                                    unsigned short* __restrict__ Ybf, int n) {
    __shared__ float Ws[F * F];   // 64 KB
    for (int i = threadIdx.x; i < F * F; i += 256) Ws[i] = W[i];
    __syncthreads();

    int lane = threadIdx.x & 31;
    int rg = threadIdx.x >> 5;
    int jc = lane * 4;
    int r0 = blockIdx.x * 64 + rg * 8;

    const float* Xf = (const float*)Xin;
    const unsigned short* Xh = (const unsigned short*)Xin;

    float4 acc[8];
    int rr[8];
#pragma unroll
    for (int i = 0; i < 8; i++) {
        acc[i] = make_float4(0.f, 0.f, 0.f, 0.f);
        int r = r0 + i;
        rr[i] = (r > n - 1) ? (n - 1) : r;
    }

    for (int k = 0; k < F; k += 4) {
        float4 w0 = *(const float4*)&Ws[(k + 0) * F + jc];
        float4 w1 = *(const float4*)&Ws[(k + 1) * F + jc];
        float4 w2 = *(const float4*)&Ws[(k + 2) * F + jc];
        float4 w3 = *(const float4*)&Ws[(k + 3) * F + jc];
#pragma unroll
        for (int i = 0; i < 8; i++) {
            float x0, x1, x2, x3;
            if (BF16IN) {
                const unsigned short* p = Xh + ((size_t)(k >> 4) * n + rr[i]) * SF + (k & 15);
                uint2 v = *(const uint2*)p;
                x0 = BF2X(v.x); x1 = BF2Y(v.x);
                x2 = BF2X(v.y); x3 = BF2Y(v.y);
            } else {
                float4 xv = *(const float4*)&Xf[(size_t)rr[i] * F + k];
                x0 = xv.x; x1 = xv.y; x2 = xv.z; x3 = xv.w;
            }
            acc[i].x = fmaf(x0, w0.x, acc[i].x); acc[i].y = fmaf(x0, w0.y, acc[i].y);
            acc[i].z = fmaf(x0, w0.z, acc[i].z); acc[i].w = fmaf(x0, w0.w, acc[i].w);
            acc[i].x = fmaf(x1, w1.x, acc[i].x); acc[i].y = fmaf(x1, w1.y, acc[i].y);
            acc[i].z = fmaf(x1, w1.z, acc[i].z); acc[i].w = fmaf(x1, w1.w, acc[i].w);
            acc[i].x = fmaf(x2, w2.x, acc[i].x); acc[i].y = fmaf(x2, w2.y, acc[i].y);
            acc[i].z = fmaf(x2, w2.z, acc[i].z); acc[i].w = fmaf(x2, w2.w, acc[i].w);
            acc[i].x = fmaf(x3, w3.x, acc[i].x); acc[i].y = fmaf(x3, w3.y, acc[i].y);
            acc[i].z = fmaf(x3, w3.z, acc[i].z); acc[i].w = fmaf(x3, w3.w, acc[i].w);
        }
    }

    int sp = jc >> 4;          // slab of this col group
    int j = jc & 15;
#pragma unroll
    for (int i = 0; i < 8; i++) {
        int r = r0 + i;
        if (r < n) {
            float s = dinv[r];
            unsigned long long pk =
                (unsigned long long)f2bf(s * acc[i].x) |
                ((unsigned long long)f2bf(s * acc[i].y) << 16) |
                ((unsigned long long)f2bf(s * acc[i].z) << 32) |
                ((unsigned long long)f2bf(s * acc[i].w) << 48);
            __builtin_nontemporal_store(pk,
                (unsigned long long*)&Ybf[((size_t)sp * n + r) * SF + j]);
        }
    }
}

// ---------------- Aggregation: XCD-pinned slabs, one wave per node ----------------
// slab = blockIdx & 7 (== XCD via round-robin). Wave lanes: ep = lane>>3 (edge slot),
// fp = lane&7 (feat pair). 8 edges in flight per VMEM instr; src loads coalesced (8 ints).
// Per-node finish: 3x shfl_xor reduce over ep, then dinv/bias/relu on lanes 0..7.

template <int WRITE_H>
__global__ __launch_bounds__(256) void agg_k(const unsigned short* __restrict__ Ybf,
                                             const float* __restrict__ dinv,
                                             const int* __restrict__ offs,
                                             const int* __restrict__ src,
                                             const float* __restrict__ bias,
                                             unsigned short* __restrict__ Hbf,
                                             float* __restrict__ gacc,
                                             int n, int waves_per_slab) {
    int slab = blockIdx.x & 7;
    int w = threadIdx.x >> 6;                                  // wave in block
    int wslot = (blockIdx.x >> 3) * 4 + w;                     // wave within slab
    int lane = threadIdx.x & 63;
    int ep = lane >> 3;
    int fp = lane & 7;
    int c2 = fp * 2;

    const unsigned short* yb = Ybf + (size_t)slab * n * SF;
    float bx = bias[slab * SF + c2];
    float by = bias[slab * SF + c2 + 1];

    float px = 0.f, py = 0.f;

    for (int g = wslot; g < n; g += waves_per_slab) {
        int s = __builtin_nontemporal_load(&offs[g]);
        int e = __builtin_nontemporal_load(&offs[g + 1]);

        unsigned int ps = *(const unsigned int*)&yb[(size_t)g * SF + c2];  // self-loop row
        float ax = (ep == 0) ? BF2X(ps) : 0.f;
        float ay = (ep == 0) ? BF2Y(ps) : 0.f;

        for (int base = s; base < e; base += 8) {
            int i = base + ep;
            int ic = (i < e) ? i : (e - 1);
            int u = __builtin_nontemporal_load(&src[ic]);
            unsigned int pv = *(const unsigned int*)&yb[(size_t)u * SF + c2];
            float m = (i < e) ? 1.f : 0.f;
            ax = fmaf(m, BF2X(pv), ax);
            ay = fmaf(m, BF2Y(pv), ay);
        }

        ax += __shfl_xor(ax, 8);  ay += __shfl_xor(ay, 8);
        ax += __shfl_xor(ax, 16); ay += __shfl_xor(ay, 16);
        ax += __shfl_xor(ax, 32); ay += __shfl_xor(ay, 32);

        if (ep == 0) {
            float dv = dinv[g];
            float hx = fmaxf(fmaf(dv, ax, bx), 0.f);
            float hy = fmaxf(fmaf(dv, ay, by), 0.f);
            if (WRITE_H) {
                unsigned int pk = (unsigned int)f2bf(hx) | ((unsigned int)f2bf(hy) << 16);
                __builtin_nontemporal_store(pk,
                    (unsigned int*)&Hbf[((size_t)slab * n + g) * SF + c2]);
            } else {
                px += hx;
                py += hy;
            }
        }
    }

    if (!WRITE_H) {
        __shared__ float2 red[4][8];
        if (ep == 0) red[w][fp] = make_float2(px, py);
        __syncthreads();
        if (threadIdx.x < 8) {
            float sx = red[0][threadIdx.x].x + red[1][threadIdx.x].x +
                       red[2][threadIdx.x].x + red[3][threadIdx.x].x;
            float sy = red[0][threadIdx.x].y + red[1][threadIdx.x].y +
                       red[2][threadIdx.x].y + red[3][threadIdx.x].y;
            atomicAdd(&gacc[slab * SF + threadIdx.x * 2], sx);
            atomicAdd(&gacc[slab * SF + threadIdx.x * 2 + 1], sy);
        }
    }
}

// ---------------- Final: out[a] = sum_k (gacc[k]/N) * Wl[k][a] + bl[a] ----------------

__global__ void final_k(const float* __restrict__ gacc, const float* __restrict__ Wl,
                        const float* __restrict__ bl, float* __restrict__ out, float invN) {
    int a = threadIdx.x;
    if (a < 16) {
        float s = bl[a];
        for (int k = 0; k < 128; k++) s = fmaf(gacc[k] * invN, Wl[k * 16 + a], s);
        out[a] = s;
    }
}

extern "C" void kernel_launch(void* const* d_in, const int* in_sizes, int n_in,
                              void* d_out, int out_size, void* d_ws, size_t ws_size,
                              hipStream_t stream) {
    const float* x  = (const float*)d_in[0];
    const int*   ei = (const int*)d_in[1];
    const float* W1 = (const float*)d_in[2];
    const float* b1 = (const float*)d_in[3];
    const float* W2 = (const float*)d_in[4];
    const float* b2 = (const float*)d_in[5];
    const float* Wl = (const float*)d_in[6];
    const float* bl = (const float*)d_in[7];

    int N = in_sizes[0] / F;
    int E = in_sizes[1] / 2;
    const int* row = ei;
    const int* col = ei + E;

    char* ws = (char*)d_ws;
    size_t off = 0;
    auto alloc = [&](size_t bytes) -> void* {
        void* p = ws + off;
        off = (off + bytes + 255) & ~(size_t)255;
        return p;
    };
    int*            cnt    = (int*)           alloc((size_t)N * 4);
    int*            offs   = (int*)           alloc((size_t)(N + 1) * 4);
    int*            cursor = (int*)           alloc((size_t)N * 4);
    float*          dinv   = (float*)         alloc((size_t)N * 4);
    int*            bsum   = (int*)           alloc(1024 * 4);
    int*            srcb   = (int*)           alloc((size_t)E * 4);
    unsigned short* ybf    = (unsigned short*)alloc((size_t)N * F * 2);
    unsigned short* hbf    = (unsigned short*)alloc((size_t)N * F * 2);
    float*          gacc   = (float*)         alloc(128 * 4);

    hipMemsetAsync(cnt, 0, (size_t)N * 4, stream);
    hipMemsetAsync(gacc, 0, 128 * 4, stream);

    int NB = (N + 1023) / 1024;
    count_edges_k<<<(E / 4 + 255) / 256, 256, 0, stream>>>(col, cnt, E);
    scan1_k<<<NB, 1024, 0, stream>>>(cnt, offs, dinv, bsum, N);
    scan2_k<<<1, 128, 0, stream>>>(bsum, NB);
    scan3_k<<<(N + 1024) / 1024, 1024, 0, stream>>>(offs, cursor, bsum, N, E);
    fill_k<<<(E + 255) / 256, 256, 0, stream>>>(row, col, cursor, srcb, E);

    int GEMM_BLOCKS = (N + 63) / 64;
    const int AGG_BLOCKS = 2048;                 // 8/CU resident; slab = blockIdx&7
    const int WAVES_PER_SLAB = (AGG_BLOCKS / 8) * 4;

    gemm_scale_k<0><<<GEMM_BLOCKS, 256, 0, stream>>>(x, W1, dinv, ybf, N);
    agg_k<1><<<AGG_BLOCKS, 256, 0, stream>>>(ybf, dinv, offs, srcb, b1, hbf, nullptr, N, WAVES_PER_SLAB);
    gemm_scale_k<1><<<GEMM_BLOCKS, 256, 0, stream>>>(hbf, W2, dinv, ybf, N);
    agg_k<0><<<AGG_BLOCKS, 256, 0, stream>>>(ybf, dinv, offs, srcb, b2, nullptr, gacc, N, WAVES_PER_SLAB);
    final_k<<<1, 64, 0, stream>>>(gacc, Wl, bl, (float*)d_out, 1.0f / (float)N);
}

// Round 5
// 734.860 us; speedup vs baseline: 1.3229x; 1.3229x over previous
//
#include <hip/hip_runtime.h>
#include <hip/hip_bf16.h>

#define F 128
#define NSLAB 4
#define SF8 32   // feats per fp8 slab

typedef float floatx2 __attribute__((ext_vector_type(2)));

static __device__ __forceinline__ float4 fp8x4_to_f32(unsigned int w) {
    floatx2 lo = __builtin_amdgcn_cvt_pk_f32_fp8((int)w, false);
    floatx2 hi = __builtin_amdgcn_cvt_pk_f32_fp8((int)w, true);
    return make_float4(lo[0], lo[1], hi[0], hi[1]);
}

static __device__ __forceinline__ unsigned int f32x4_to_fp8(float a, float b, float c, float d) {
    int w = 0;
    w = __builtin_amdgcn_cvt_pk_fp8_f32(a, b, w, false);
    w = __builtin_amdgcn_cvt_pk_fp8_f32(c, d, w, true);
    return (unsigned int)w;
}

// ---------------- CSR build ----------------

__global__ void count_edges_k(const int* __restrict__ col, int* __restrict__ cnt, int E) {
    int e0 = (blockIdx.x * 256 + threadIdx.x) * 4;
    if (e0 + 4 <= E) {
        int4 c = *(const int4*)&col[e0];
        atomicAdd(&cnt[c.x], 1);
        atomicAdd(&cnt[c.y], 1);
        atomicAdd(&cnt[c.z], 1);
        atomicAdd(&cnt[c.w], 1);
    } else {
        for (int e = e0; e < E; e++) atomicAdd(&cnt[col[e]], 1);
    }
}

__global__ void scan1_k(const int* __restrict__ cnt, int* __restrict__ offs,
                        float* __restrict__ dinv, int* __restrict__ bsum, int n) {
    __shared__ int s[1024];
    int tid = threadIdx.x;
    int i = blockIdx.x * 1024 + tid;
    int v = (i < n) ? cnt[i] : 0;
    s[tid] = v;
    __syncthreads();
    for (int off = 1; off < 1024; off <<= 1) {
        int t = (tid >= off) ? s[tid - off] : 0;
        __syncthreads();
        s[tid] += t;
        __syncthreads();
    }
    if (i < n) {
        offs[i] = s[tid] - v;
        dinv[i] = rsqrtf((float)(v + 1));
    }
    if (tid == 1023) bsum[blockIdx.x] = s[1023];
}

__global__ void scan2_k(int* bsum, int nb) {
    __shared__ int s[128];
    int tid = threadIdx.x;
    int v = (tid < nb) ? bsum[tid] : 0;
    s[tid] = v;
    __syncthreads();
    for (int off = 1; off < 128; off <<= 1) {
        int t = (tid >= off) ? s[tid - off] : 0;
        __syncthreads();
        s[tid] += t;
        __syncthreads();
    }
    if (tid < nb) bsum[tid] = s[tid] - v;
}

__global__ void scan3_k(int* __restrict__ offs, int* __restrict__ cursor,
                        const int* __restrict__ bsum, int n, int E) {
    int i = blockIdx.x * 1024 + threadIdx.x;
    if (i < n) {
        int o = offs[i] + bsum[blockIdx.x];
        offs[i] = o;
        cursor[i] = o;
    }
    if (i == n) offs[n] = E;
}

__global__ void fill_k(const int* __restrict__ row, const int* __restrict__ col,
                       int* __restrict__ cursor, int* __restrict__ src, int E) {
    int e0 = (blockIdx.x * 256 + threadIdx.x) * 4;
    if (e0 + 4 <= E) {
        int4 r4 = *(const int4*)&row[e0];
        int4 c4 = *(const int4*)&col[e0];
        src[atomicAdd(&cursor[c4.x], 1)] = r4.x;
        src[atomicAdd(&cursor[c4.y], 1)] = r4.y;
        src[atomicAdd(&cursor[c4.z], 1)] = r4.z;
        src[atomicAdd(&cursor[c4.w], 1)] = r4.w;
    } else {
        for (int e = e0; e < E; e++) {
            int v = col[e];
            int pos = atomicAdd(&cursor[v], 1);
            src[pos] = row[e];
        }
    }
}

// ---------------- GEMM: Y8[p][r][32] = fp8( dinv[r] * (X[r,:] @ W) ) ----------------
// FP8IN=0: X is f32 row-major [n][128]. FP8IN=1: X is fp8 slab-major [4][n][32].

template <int FP8IN>
__global__ __launch_bounds__(256) void gemm_scale_k(const void* __restrict__ Xin,
                                                    const float* __restrict__ W,
                                                    const float* __restrict__ dinv,
                                                    unsigned char* __restrict__ Y8, int n) {
    __shared__ float Ws[F * F];   // 64 KB
    for (int i = threadIdx.x; i < F * F; i += 256) Ws[i] = W[i];
    __syncthreads();

    int lane = threadIdx.x & 31;
    int rg = threadIdx.x >> 5;
    int jc = lane * 4;
    int r0 = blockIdx.x * 64 + rg * 8;

    const float* Xf = (const float*)Xin;
    const unsigned char* X8 = (const unsigned char*)Xin;

    float4 acc[8];
    int rr[8];
#pragma unroll
    for (int i = 0; i < 8; i++) {
        acc[i] = make_float4(0.f, 0.f, 0.f, 0.f);
        int r = r0 + i;
        rr[i] = (r > n - 1) ? (n - 1) : r;
    }

    for (int k = 0; k < F; k += 4) {
        float4 w0 = *(const float4*)&Ws[(k + 0) * F + jc];
        float4 w1 = *(const float4*)&Ws[(k + 1) * F + jc];
        float4 w2 = *(const float4*)&Ws[(k + 2) * F + jc];
        float4 w3 = *(const float4*)&Ws[(k + 3) * F + jc];
#pragma unroll
        for (int i = 0; i < 8; i++) {
            float4 xv;
            if (FP8IN) {
                unsigned int v = *(const unsigned int*)
                    &X8[((size_t)(k >> 5) * n + rr[i]) * SF8 + (k & 31)];
                xv = fp8x4_to_f32(v);
            } else {
                xv = *(const float4*)&Xf[(size_t)rr[i] * F + k];
            }
            acc[i].x = fmaf(xv.x, w0.x, acc[i].x); acc[i].y = fmaf(xv.x, w0.y, acc[i].y);
            acc[i].z = fmaf(xv.x, w0.z, acc[i].z); acc[i].w = fmaf(xv.x, w0.w, acc[i].w);
            acc[i].x = fmaf(xv.y, w1.x, acc[i].x); acc[i].y = fmaf(xv.y, w1.y, acc[i].y);
            acc[i].z = fmaf(xv.y, w1.z, acc[i].z); acc[i].w = fmaf(xv.y, w1.w, acc[i].w);
            acc[i].x = fmaf(xv.z, w2.x, acc[i].x); acc[i].y = fmaf(xv.z, w2.y, acc[i].y);
            acc[i].z = fmaf(xv.z, w2.z, acc[i].z); acc[i].w = fmaf(xv.z, w2.w, acc[i].w);
            acc[i].x = fmaf(xv.w, w3.x, acc[i].x); acc[i].y = fmaf(xv.w, w3.y, acc[i].y);
            acc[i].z = fmaf(xv.w, w3.z, acc[i].z); acc[i].w = fmaf(xv.w, w3.w, acc[i].w);
        }
    }

    int sp = jc >> 5;          // slab of this col group
    int j = jc & 31;
#pragma unroll
    for (int i = 0; i < 8; i++) {
        int r = r0 + i;
        if (r < n) {
            float s = dinv[r];
            unsigned int pk = f32x4_to_fp8(s * acc[i].x, s * acc[i].y,
                                           s * acc[i].z, s * acc[i].w);
            __builtin_nontemporal_store(pk,
                (unsigned int*)&Y8[((size_t)sp * n + r) * SF8 + j]);
        }
    }
}

// ---------------- Aggregation: XCD-pinned fp8 slabs, 8-lane group per node ----------------
// slab = blockIdx & 3 (each XCD sees exactly one slab under mod-8 dispatch).
// Lane reads 4 fp8 feats (1 uint) per edge; 4-unrolled independent gathers.

template <int WRITE_H>
__global__ __launch_bounds__(256) void agg_k(const unsigned char* __restrict__ Y8,
                                             const float* __restrict__ dinv,
                                             const int* __restrict__ offs,
                                             const int* __restrict__ src,
                                             const float* __restrict__ bias,
                                             unsigned char* __restrict__ H8,
                                             float* __restrict__ gacc, int n) {
    int slab = blockIdx.x & 3;
    int nb = blockIdx.x >> 2;
    int grp = threadIdx.x >> 3;        // 0..31
    int l8 = threadIdx.x & 7;          // 0..7
    int g = nb * 32 + grp;
    const unsigned int* yb = (const unsigned int*)(Y8 + (size_t)slab * n * SF8);

    float4 h = make_float4(0.f, 0.f, 0.f, 0.f);
    if (g < n) {
        float4 a0 = fp8x4_to_f32(yb[(size_t)g * 8 + l8]);   // self-loop
        float4 a1 = make_float4(0.f, 0.f, 0.f, 0.f);
        float4 a2 = make_float4(0.f, 0.f, 0.f, 0.f);
        float4 a3 = make_float4(0.f, 0.f, 0.f, 0.f);

        int s = offs[g], e = offs[g + 1];
        int i = s;
        for (; i + 4 <= e; i += 4) {
            int u0 = src[i], u1 = src[i + 1], u2 = src[i + 2], u3 = src[i + 3];
            float4 t0 = fp8x4_to_f32(yb[(size_t)u0 * 8 + l8]);
            float4 t1 = fp8x4_to_f32(yb[(size_t)u1 * 8 + l8]);
            float4 t2 = fp8x4_to_f32(yb[(size_t)u2 * 8 + l8]);
            float4 t3 = fp8x4_to_f32(yb[(size_t)u3 * 8 + l8]);
            a0.x += t0.x; a0.y += t0.y; a0.z += t0.z; a0.w += t0.w;
            a1.x += t1.x; a1.y += t1.y; a1.z += t1.z; a1.w += t1.w;
            a2.x += t2.x; a2.y += t2.y; a2.z += t2.z; a2.w += t2.w;
            a3.x += t3.x; a3.y += t3.y; a3.z += t3.z; a3.w += t3.w;
        }
        for (; i < e; i++) {
            float4 t = fp8x4_to_f32(yb[(size_t)src[i] * 8 + l8]);
            a0.x += t.x; a0.y += t.y; a0.z += t.z; a0.w += t.w;
        }

        float dv = dinv[g];
        float4 b = ((const float4*)bias)[slab * 8 + l8];
        h.x = fmaxf(fmaf(dv, a0.x + a1.x + a2.x + a3.x, b.x), 0.f);
        h.y = fmaxf(fmaf(dv, a0.y + a1.y + a2.y + a3.y, b.y), 0.f);
        h.z = fmaxf(fmaf(dv, a0.z + a1.z + a2.z + a3.z, b.z), 0.f);
        h.w = fmaxf(fmaf(dv, a0.w + a1.w + a2.w + a3.w, b.w), 0.f);

        if (WRITE_H) {
            unsigned int pk = f32x4_to_fp8(h.x, h.y, h.z, h.w);
            __builtin_nontemporal_store(pk,
                (unsigned int*)&H8[((size_t)slab * n + g) * SF8 + l8 * 4]);
        }
    }

    if (!WRITE_H) {
        __shared__ float4 red[256];
        red[threadIdx.x] = h;
        __syncthreads();
        for (int sft = 128; sft >= 8; sft >>= 1) {
            if (threadIdx.x < sft) {
                red[threadIdx.x].x += red[threadIdx.x + sft].x;
                red[threadIdx.x].y += red[threadIdx.x + sft].y;
                red[threadIdx.x].z += red[threadIdx.x + sft].z;
                red[threadIdx.x].w += red[threadIdx.x + sft].w;
            }
            __syncthreads();
        }
        if (threadIdx.x < 8) {
            float4 v = red[threadIdx.x];
            atomicAdd(&gacc[slab * SF8 + threadIdx.x * 4 + 0], v.x);
            atomicAdd(&gacc[slab * SF8 + threadIdx.x * 4 + 1], v.y);
            atomicAdd(&gacc[slab * SF8 + threadIdx.x * 4 + 2], v.z);
            atomicAdd(&gacc[slab * SF8 + threadIdx.x * 4 + 3], v.w);
        }
    }
}

// ---------------- Final: out[a] = sum_k (gacc[k]/N) * Wl[k][a] + bl[a] ----------------

__global__ void final_k(const float* __restrict__ gacc, const float* __restrict__ Wl,
                        const float* __restrict__ bl, float* __restrict__ out, float invN) {
    int a = threadIdx.x;
    if (a < 16) {
        float s = bl[a];
        for (int k = 0; k < 128; k++) s = fmaf(gacc[k] * invN, Wl[k * 16 + a], s);
        out[a] = s;
    }
}

extern "C" void kernel_launch(void* const* d_in, const int* in_sizes, int n_in,
                              void* d_out, int out_size, void* d_ws, size_t ws_size,
                              hipStream_t stream) {
    const float* x  = (const float*)d_in[0];
    const int*   ei = (const int*)d_in[1];
    const float* W1 = (const float*)d_in[2];
    const float* b1 = (const float*)d_in[3];
    const float* W2 = (const float*)d_in[4];
    const float* b2 = (const float*)d_in[5];
    const float* Wl = (const float*)d_in[6];
    const float* bl = (const float*)d_in[7];

    int N = in_sizes[0] / F;
    int E = in_sizes[1] / 2;
    const int* row = ei;
    const int* col = ei + E;

    char* ws = (char*)d_ws;
    size_t off = 0;
    auto alloc = [&](size_t bytes) -> void* {
        void* p = ws + off;
        off = (off + bytes + 255) & ~(size_t)255;
        return p;
    };
    int*           cnt    = (int*)           alloc((size_t)N * 4);
    int*           offs   = (int*)           alloc((size_t)(N + 1) * 4);
    int*           cursor = (int*)           alloc((size_t)N * 4);
    float*         dinv   = (float*)         alloc((size_t)N * 4);
    int*           bsum   = (int*)           alloc(1024 * 4);
    int*           srcb   = (int*)           alloc((size_t)E * 4);
    unsigned char* ybf8   = (unsigned char*) alloc((size_t)N * F);
    unsigned char* hbf8   = (unsigned char*) alloc((size_t)N * F);
    float*         gacc   = (float*)         alloc(128 * 4);

    hipMemsetAsync(cnt, 0, (size_t)N * 4, stream);
    hipMemsetAsync(gacc, 0, 128 * 4, stream);

    int NB = (N + 1023) / 1024;
    count_edges_k<<<(E / 4 + 255) / 256, 256, 0, stream>>>(col, cnt, E);
    scan1_k<<<NB, 1024, 0, stream>>>(cnt, offs, dinv, bsum, N);
    scan2_k<<<1, 128, 0, stream>>>(bsum, NB);
    scan3_k<<<(N + 1024) / 1024, 1024, 0, stream>>>(offs, cursor, bsum, N, E);
    fill_k<<<(E / 4 + 255) / 256, 256, 0, stream>>>(row, col, cursor, srcb, E);

    int GEMM_BLOCKS = (N + 63) / 64;
    int AGG_BLOCKS = NSLAB * ((N + 31) / 32);

    gemm_scale_k<0><<<GEMM_BLOCKS, 256, 0, stream>>>(x, W1, dinv, ybf8, N);
    agg_k<1><<<AGG_BLOCKS, 256, 0, stream>>>(ybf8, dinv, offs, srcb, b1, hbf8, nullptr, N);
    gemm_scale_k<1><<<GEMM_BLOCKS, 256, 0, stream>>>(hbf8, W2, dinv, ybf8, N);
    agg_k<0><<<AGG_BLOCKS, 256, 0, stream>>>(ybf8, dinv, offs, srcb, b2, nullptr, gacc, N);
    final_k<<<1, 64, 0, stream>>>(gacc, Wl, bl, (float*)d_out, 1.0f / (float)N);
}

// Round 6
// 600.757 us; speedup vs baseline: 1.6182x; 1.2232x over previous
//
#include <hip/hip_runtime.h>
#include <hip/hip_bf16.h>

#define F 128

typedef float floatx2 __attribute__((ext_vector_type(2)));

static __device__ __forceinline__ float4 fp8x4_to_f32(unsigned int w) {
    floatx2 lo = __builtin_amdgcn_cvt_pk_f32_fp8((int)w, false);
    floatx2 hi = __builtin_amdgcn_cvt_pk_f32_fp8((int)w, true);
    return make_float4(lo[0], lo[1], hi[0], hi[1]);
}

static __device__ __forceinline__ unsigned int f32x4_to_fp8(float a, float b, float c, float d) {
    int w = 0;
    w = __builtin_amdgcn_cvt_pk_fp8_f32(a, b, w, false);
    w = __builtin_amdgcn_cvt_pk_fp8_f32(c, d, w, true);
    return (unsigned int)w;
}

// ---------------- CSR build ----------------

__global__ void count_edges_k(const int* __restrict__ col, int* __restrict__ cnt, int E) {
    int e0 = (blockIdx.x * 256 + threadIdx.x) * 4;
    if (e0 + 4 <= E) {
        int4 c = *(const int4*)&col[e0];
        atomicAdd(&cnt[c.x], 1);
        atomicAdd(&cnt[c.y], 1);
        atomicAdd(&cnt[c.z], 1);
        atomicAdd(&cnt[c.w], 1);
    } else {
        for (int e = e0; e < E; e++) atomicAdd(&cnt[col[e]], 1);
    }
}

__global__ void scan1_k(const int* __restrict__ cnt, int* __restrict__ offs,
                        float* __restrict__ dinv, int* __restrict__ bsum, int n) {
    __shared__ int s[1024];
    int tid = threadIdx.x;
    int i = blockIdx.x * 1024 + tid;
    int v = (i < n) ? cnt[i] : 0;
    s[tid] = v;
    __syncthreads();
    for (int off = 1; off < 1024; off <<= 1) {
        int t = (tid >= off) ? s[tid - off] : 0;
        __syncthreads();
        s[tid] += t;
        __syncthreads();
    }
    if (i < n) {
        offs[i] = s[tid] - v;
        dinv[i] = rsqrtf((float)(v + 1));
    }
    if (tid == 1023) bsum[blockIdx.x] = s[1023];
}

__global__ void scan2_k(int* bsum, int nb) {
    __shared__ int s[128];
    int tid = threadIdx.x;
    int v = (tid < nb) ? bsum[tid] : 0;
    s[tid] = v;
    __syncthreads();
    for (int off = 1; off < 128; off <<= 1) {
        int t = (tid >= off) ? s[tid - off] : 0;
        __syncthreads();
        s[tid] += t;
        __syncthreads();
    }
    if (tid < nb) bsum[tid] = s[tid] - v;
}

__global__ void scan3_k(int* __restrict__ offs, int* __restrict__ cursor,
                        const int* __restrict__ bsum, int n, int E) {
    int i = blockIdx.x * 1024 + threadIdx.x;
    if (i < n) {
        int o = offs[i] + bsum[blockIdx.x];
        offs[i] = o;
        cursor[i] = o;
    }
    if (i == n) offs[n] = E;
}

__global__ void fill_k(const int* __restrict__ row, const int* __restrict__ col,
                       int* __restrict__ cursor, int* __restrict__ src, int E) {
    int e0 = (blockIdx.x * 256 + threadIdx.x) * 4;
    if (e0 + 4 <= E) {
        int4 r4 = *(const int4*)&row[e0];
        int4 c4 = *(const int4*)&col[e0];
        src[atomicAdd(&cursor[c4.x], 1)] = r4.x;
        src[atomicAdd(&cursor[c4.y], 1)] = r4.y;
        src[atomicAdd(&cursor[c4.z], 1)] = r4.z;
        src[atomicAdd(&cursor[c4.w], 1)] = r4.w;
    } else {
        for (int e = e0; e < E; e++) {
            int v = col[e];
            int pos = atomicAdd(&cursor[v], 1);
            src[pos] = row[e];
        }
    }
}

// ---------------- GEMM: Y8[r][128] = fp8( dinv[r] * (X[r,:] @ W) ), row-major fp8 ----------------
// FP8IN=0: X is f32 row-major [n][128]. FP8IN=1: X is fp8 row-major [n][128].

template <int FP8IN>
__global__ __launch_bounds__(256) void gemm_scale_k(const void* __restrict__ Xin,
                                                    const float* __restrict__ W,
                                                    const float* __restrict__ dinv,
                                                    unsigned int* __restrict__ Y8, int n) {
    __shared__ float Ws[F * F];   // 64 KB
    for (int i = threadIdx.x; i < F * F; i += 256) Ws[i] = W[i];
    __syncthreads();

    int lane = threadIdx.x & 31;
    int rg = threadIdx.x >> 5;
    int jc = lane * 4;
    int r0 = blockIdx.x * 64 + rg * 8;

    const float* Xf = (const float*)Xin;
    const unsigned int* Xu = (const unsigned int*)Xin;

    float4 acc[8];
    int rr[8];
#pragma unroll
    for (int i = 0; i < 8; i++) {
        acc[i] = make_float4(0.f, 0.f, 0.f, 0.f);
        int r = r0 + i;
        rr[i] = (r > n - 1) ? (n - 1) : r;
    }

    for (int k = 0; k < F; k += 4) {
        float4 w0 = *(const float4*)&Ws[(k + 0) * F + jc];
        float4 w1 = *(const float4*)&Ws[(k + 1) * F + jc];
        float4 w2 = *(const float4*)&Ws[(k + 2) * F + jc];
        float4 w3 = *(const float4*)&Ws[(k + 3) * F + jc];
#pragma unroll
        for (int i = 0; i < 8; i++) {
            float4 xv;
            if (FP8IN) {
                xv = fp8x4_to_f32(Xu[(size_t)rr[i] * 32 + (k >> 2)]);
            } else {
                xv = *(const float4*)&Xf[(size_t)rr[i] * F + k];
            }
            acc[i].x = fmaf(xv.x, w0.x, acc[i].x); acc[i].y = fmaf(xv.x, w0.y, acc[i].y);
            acc[i].z = fmaf(xv.x, w0.z, acc[i].z); acc[i].w = fmaf(xv.x, w0.w, acc[i].w);
            acc[i].x = fmaf(xv.y, w1.x, acc[i].x); acc[i].y = fmaf(xv.y, w1.y, acc[i].y);
            acc[i].z = fmaf(xv.y, w1.z, acc[i].z); acc[i].w = fmaf(xv.y, w1.w, acc[i].w);
            acc[i].x = fmaf(xv.z, w2.x, acc[i].x); acc[i].y = fmaf(xv.z, w2.y, acc[i].y);
            acc[i].z = fmaf(xv.z, w2.z, acc[i].z); acc[i].w = fmaf(xv.z, w2.w, acc[i].w);
            acc[i].x = fmaf(xv.w, w3.x, acc[i].x); acc[i].y = fmaf(xv.w, w3.y, acc[i].y);
            acc[i].z = fmaf(xv.w, w3.z, acc[i].z); acc[i].w = fmaf(xv.w, w3.w, acc[i].w);
        }
    }

#pragma unroll
    for (int i = 0; i < 8; i++) {
        int r = r0 + i;
        if (r < n) {
            float s = dinv[r];
            unsigned int pk = f32x4_to_fp8(s * acc[i].x, s * acc[i].y,
                                           s * acc[i].z, s * acc[i].w);
            __builtin_nontemporal_store(pk, &Y8[(size_t)r * 32 + lane]);
        }
    }
}

// ---------------- Aggregation: 32-lane group per node, 1 cacheline per edge ----------------
// Row-major fp8 [n][128]: one node row = 128 B = 1 line, read by 32 lanes (uint each).
// 4 gathers in flight (masked clamp unroll, no serial tail). Grid-strided, 2048 blocks.

template <int WRITE_H>
__global__ __launch_bounds__(256) void agg_k(const unsigned int* __restrict__ Y8,
                                             const float* __restrict__ dinv,
                                             const int* __restrict__ offs,
                                             const int* __restrict__ src,
                                             const float* __restrict__ bias,
                                             unsigned int* __restrict__ H8,
                                             float* __restrict__ gacc,
                                             int n, int ngroups) {
    int l = threadIdx.x & 31;
    int grp0 = (blockIdx.x * 256 + threadIdx.x) >> 5;

    float4 b = ((const float4*)bias)[l];
    float4 pacc = make_float4(0.f, 0.f, 0.f, 0.f);

    for (int g = grp0; g < n; g += ngroups) {
        float4 a0 = fp8x4_to_f32(Y8[(size_t)g * 32 + l]);   // self-loop
        float4 a1 = make_float4(0.f, 0.f, 0.f, 0.f);
        float4 a2 = make_float4(0.f, 0.f, 0.f, 0.f);
        float4 a3 = make_float4(0.f, 0.f, 0.f, 0.f);

        int s = offs[g], e = offs[g + 1];
        for (int base = s; base < e; base += 4) {
            int i1 = base + 1, i2 = base + 2, i3 = base + 3;
            int u0 = src[base];
            int u1 = src[(i1 < e) ? i1 : base];
            int u2 = src[(i2 < e) ? i2 : base];
            int u3 = src[(i3 < e) ? i3 : base];
            float m1 = (i1 < e) ? 1.f : 0.f;
            float m2 = (i2 < e) ? 1.f : 0.f;
            float m3 = (i3 < e) ? 1.f : 0.f;
            float4 t0 = fp8x4_to_f32(Y8[(size_t)u0 * 32 + l]);
            float4 t1 = fp8x4_to_f32(Y8[(size_t)u1 * 32 + l]);
            float4 t2 = fp8x4_to_f32(Y8[(size_t)u2 * 32 + l]);
            float4 t3 = fp8x4_to_f32(Y8[(size_t)u3 * 32 + l]);
            a0.x += t0.x; a0.y += t0.y; a0.z += t0.z; a0.w += t0.w;
            a1.x = fmaf(m1, t1.x, a1.x); a1.y = fmaf(m1, t1.y, a1.y);
            a1.z = fmaf(m1, t1.z, a1.z); a1.w = fmaf(m1, t1.w, a1.w);
            a2.x = fmaf(m2, t2.x, a2.x); a2.y = fmaf(m2, t2.y, a2.y);
            a2.z = fmaf(m2, t2.z, a2.z); a2.w = fmaf(m2, t2.w, a2.w);
            a3.x = fmaf(m3, t3.x, a3.x); a3.y = fmaf(m3, t3.y, a3.y);
            a3.z = fmaf(m3, t3.z, a3.z); a3.w = fmaf(m3, t3.w, a3.w);
        }

        float dv = dinv[g];
        float4 h;
        h.x = fmaxf(fmaf(dv, a0.x + a1.x + a2.x + a3.x, b.x), 0.f);
        h.y = fmaxf(fmaf(dv, a0.y + a1.y + a2.y + a3.y, b.y), 0.f);
        h.z = fmaxf(fmaf(dv, a0.z + a1.z + a2.z + a3.z, b.z), 0.f);
        h.w = fmaxf(fmaf(dv, a0.w + a1.w + a2.w + a3.w, b.w), 0.f);

        if (WRITE_H) {
            __builtin_nontemporal_store(f32x4_to_fp8(h.x, h.y, h.z, h.w),
                                        &H8[(size_t)g * 32 + l]);
        } else {
            pacc.x += h.x; pacc.y += h.y; pacc.z += h.z; pacc.w += h.w;
        }
    }

    if (!WRITE_H) {
        __shared__ float4 red[256];
        red[threadIdx.x] = pacc;
        __syncthreads();
        if (threadIdx.x < 32) {
            float4 a = red[threadIdx.x];
#pragma unroll
            for (int t = 32; t < 256; t += 32) {
                a.x += red[threadIdx.x + t].x;
                a.y += red[threadIdx.x + t].y;
                a.z += red[threadIdx.x + t].z;
                a.w += red[threadIdx.x + t].w;
            }
            atomicAdd(&gacc[threadIdx.x * 4 + 0], a.x);
            atomicAdd(&gacc[threadIdx.x * 4 + 1], a.y);
            atomicAdd(&gacc[threadIdx.x * 4 + 2], a.z);
            atomicAdd(&gacc[threadIdx.x * 4 + 3], a.w);
        }
    }
}

// ---------------- Final: out[a] = sum_k (gacc[k]/N) * Wl[k][a] + bl[a] ----------------

__global__ void final_k(const float* __restrict__ gacc, const float* __restrict__ Wl,
                        const float* __restrict__ bl, float* __restrict__ out, float invN) {
    int a = threadIdx.x;
    if (a < 16) {
        float s = bl[a];
        for (int k = 0; k < 128; k++) s = fmaf(gacc[k] * invN, Wl[k * 16 + a], s);
        out[a] = s;
    }
}

extern "C" void kernel_launch(void* const* d_in, const int* in_sizes, int n_in,
                              void* d_out, int out_size, void* d_ws, size_t ws_size,
                              hipStream_t stream) {
    const float* x  = (const float*)d_in[0];
    const int*   ei = (const int*)d_in[1];
    const float* W1 = (const float*)d_in[2];
    const float* b1 = (const float*)d_in[3];
    const float* W2 = (const float*)d_in[4];
    const float* b2 = (const float*)d_in[5];
    const float* Wl = (const float*)d_in[6];
    const float* bl = (const float*)d_in[7];

    int N = in_sizes[0] / F;
    int E = in_sizes[1] / 2;
    const int* row = ei;
    const int* col = ei + E;

    char* ws = (char*)d_ws;
    size_t off = 0;
    auto alloc = [&](size_t bytes) -> void* {
        void* p = ws + off;
        off = (off + bytes + 255) & ~(size_t)255;
        return p;
    };
    int*          cnt    = (int*)          alloc((size_t)N * 4);
    int*          offs   = (int*)          alloc((size_t)(N + 1) * 4);
    int*          cursor = (int*)          alloc((size_t)N * 4);
    float*        dinv   = (float*)        alloc((size_t)N * 4);
    int*          bsum   = (int*)          alloc(1024 * 4);
    int*          srcb   = (int*)          alloc((size_t)E * 4);
    unsigned int* ybf8   = (unsigned int*) alloc((size_t)N * F);
    unsigned int* hbf8   = (unsigned int*) alloc((size_t)N * F);
    float*        gacc   = (float*)        alloc(128 * 4);

    hipMemsetAsync(cnt, 0, (size_t)N * 4, stream);
    hipMemsetAsync(gacc, 0, 128 * 4, stream);

    int NB = (N + 1023) / 1024;
    count_edges_k<<<(E / 4 + 255) / 256, 256, 0, stream>>>(col, cnt, E);
    scan1_k<<<NB, 1024, 0, stream>>>(cnt, offs, dinv, bsum, N);
    scan2_k<<<1, 128, 0, stream>>>(bsum, NB);
    scan3_k<<<(N + 1024) / 1024, 1024, 0, stream>>>(offs, cursor, bsum, N, E);
    fill_k<<<(E / 4 + 255) / 256, 256, 0, stream>>>(row, col, cursor, srcb, E);

    int GEMM_BLOCKS = (N + 63) / 64;
    const int AGG_BLOCKS = 2048;                  // 8 blocks/CU
    const int NGROUPS = AGG_BLOCKS * 8;           // 32-lane groups

    gemm_scale_k<0><<<GEMM_BLOCKS, 256, 0, stream>>>(x, W1, dinv, ybf8, N);
    agg_k<1><<<AGG_BLOCKS, 256, 0, stream>>>(ybf8, dinv, offs, srcb, b1, hbf8, nullptr, N, NGROUPS);
    gemm_scale_k<1><<<GEMM_BLOCKS, 256, 0, stream>>>(hbf8, W2, dinv, ybf8, N);
    agg_k<0><<<AGG_BLOCKS, 256, 0, stream>>>(ybf8, dinv, offs, srcb, b2, nullptr, gacc, N, NGROUPS);
    final_k<<<1, 64, 0, stream>>>(gacc, Wl, bl, (float*)d_out, 1.0f / (float)N);
}